// Round 1
// baseline (3343.324 us; speedup 1.0000x reference)
//
#include <hip/hip_runtime.h>
#include <math.h>

#define T_ 4096
#define D_ 1024
#define H_ 16
#define DH_ 64
#define E_ 8
#define CAP_ 1024
#define MLP_ 4096
#define HOPS_ 3

// ================================================================ embed
__global__ __launch_bounds__(256) void embed_kernel(
    const int* __restrict__ ids, const float* __restrict__ ew, float* __restrict__ h)
{
  const int t = blockIdx.x;
  const int id = ids[t];
  const int c = threadIdx.x * 4;
  *(float4*)(h + (size_t)t * D_ + c) = *(const float4*)(ew + (size_t)id * D_ + c);
}

// ================================================================ router
__global__ __launch_bounds__(64) void router_kernel(
    const float* __restrict__ h, const float* __restrict__ rw,
    float* __restrict__ probs, float* __restrict__ gmask)
{
  const int t = blockIdx.x;
  const int lane = threadIdx.x;
  __shared__ float hs[D_];
  #pragma unroll
  for (int j = 0; j < 4; ++j)
    *(float4*)&hs[lane * 4 + j * 256] = *(const float4*)(h + (size_t)t * D_ + lane * 4 + j * 256);
  __syncthreads();
  float l9[9];
  #pragma unroll
  for (int e = 0; e < 9; ++e) {
    float s = 0.0f;
    for (int i = lane; i < D_; i += 64) s += hs[i] * rw[e * D_ + i];
    #pragma unroll
    for (int off = 32; off > 0; off >>= 1) s += __shfl_down(s, off);
    l9[e] = s;
  }
  if (lane == 0) {
    float m = l9[0];
    #pragma unroll
    for (int e = 1; e < 9; ++e) m = fmaxf(m, l9[e]);
    float sum = 0.0f;
    float ex[9];
    #pragma unroll
    for (int e = 0; e < 9; ++e) { ex[e] = expf(l9[e] - m); sum += ex[e]; }
    const float inv = 1.0f / sum;
    int b1 = 0;
    #pragma unroll
    for (int e = 1; e < 9; ++e) if (l9[e] > l9[b1]) b1 = e;
    int b2 = (b1 == 0) ? 1 : 0;
    #pragma unroll
    for (int e = 0; e < 9; ++e) if (e != b1 && e != b2 && l9[e] > l9[b2]) b2 = e;
    #pragma unroll
    for (int e = 0; e < 8; ++e) {
      const float pe = ex[e] * inv;
      probs[t * 8 + e] = pe;
      gmask[(size_t)e * T_ + t] = (e == b1 || e == b2) ? pe : -1e30f;
    }
  }
}

// ================================================================ zero
__global__ __launch_bounds__(256) void zero_kernel(float* __restrict__ rho, int* __restrict__ cnt)
{
  const int i = blockIdx.x * 256 + threadIdx.x;
  if (i < T_) rho[i] = 0.0f;
  if (i < E_) cnt[i] = 0;
}

__global__ __launch_bounds__(256) void zeroeo_kernel(float* __restrict__ eo)
{
  const size_t i = ((size_t)blockIdx.x * 256 + threadIdx.x) * 4;
  float4 z; z.x = z.y = z.z = z.w = 0.0f;
  *(float4*)(eo + i) = z;
}

// ================================================================ capacity select (rank-based)
__global__ __launch_bounds__(256) void select_kernel(
    const float* __restrict__ gmask, const float* __restrict__ probs,
    int* __restrict__ idx, int* __restrict__ cnt, float* __restrict__ rho)
{
  __shared__ float row[T_];
  const int e = blockIdx.y;
  const int tid = threadIdx.x;
  const float* gr = gmask + (size_t)e * T_;
  #pragma unroll
  for (int j = 0; j < 16; ++j) row[tid + 256 * j] = gr[tid + 256 * j];
  __syncthreads();
  const int t = blockIdx.x * 256 + tid;
  const float g = row[t];
  if (g > -1e29f) {
    int rank = 0;
    for (int tt = 0; tt < T_; ++tt) {
      const float gg = row[tt];
      rank += (gg > g) || (gg == g && tt < t);
    }
    if (rank < CAP_) {
      const int pos = atomicAdd(&cnt[e], 1);
      idx[e * CAP_ + pos] = t;
      atomicAdd(&rho[t], probs[t * 8 + e]);
    }
  }
}

// ================================================================ bf16 helpers
typedef __bf16 bf16x8 __attribute__((ext_vector_type(8)));
typedef float f32x4v __attribute__((ext_vector_type(4)));

union FragU { uint2 u2[2]; bf16x8 v; };

__device__ __forceinline__ unsigned pack_hi2(unsigned u0, unsigned u1)
{
  return (u0 >> 16) | (u1 & 0xFFFF0000u);
}

__device__ __forceinline__ void split8(const float4 a, const float4 b, FragU& h, FragU& l)
{
  const float f[8] = {a.x, a.y, a.z, a.w, b.x, b.y, b.z, b.w};
  unsigned hu[8], lu[8];
  #pragma unroll
  for (int i = 0; i < 8; ++i) {
    const unsigned u = __float_as_uint(f[i]);
    const float lo = f[i] - __uint_as_float(u & 0xFFFF0000u);
    hu[i] = u; lu[i] = __float_as_uint(lo);
  }
  h.u2[0].x = pack_hi2(hu[0], hu[1]); h.u2[0].y = pack_hi2(hu[2], hu[3]);
  h.u2[1].x = pack_hi2(hu[4], hu[5]); h.u2[1].y = pack_hi2(hu[6], hu[7]);
  l.u2[0].x = pack_hi2(lu[0], lu[1]); l.u2[0].y = pack_hi2(lu[2], lu[3]);
  l.u2[1].x = pack_hi2(lu[4], lu[5]); l.u2[1].y = pack_hi2(lu[6], lu[7]);
}

__device__ __forceinline__ void lds_load16(const void* g, void* l)
{
  __builtin_amdgcn_global_load_lds(
      (const __attribute__((address_space(1))) unsigned int*)g,
      (__attribute__((address_space(3))) unsigned int*)l, 16, 0, 0);
}

__device__ __forceinline__ float gelu_tanh(float x)
{
  const float x3 = x * x * x;
  return 0.5f * x * (1.0f + tanhf(0.7978845608028654f * (x + 0.044715f * x3)));
}

// ================================================================ gather (writes split-bf16 xin')
// xin' layout per row: [2*D_] shorts, hi at [0,D), lo at [D,2D)
__global__ __launch_bounds__(256) void gather_kernel(
    const float* __restrict__ h, const int* __restrict__ idx, const int* __restrict__ cnt,
    unsigned short* __restrict__ xinp)
{
  const int c = blockIdx.x, e = blockIdx.y;
  const int c4 = threadIdx.x * 4;
  unsigned short* dst = xinp + ((size_t)e * CAP_ + c) * 2 * D_;
  if (c < cnt[e]) {
    const int t = idx[e * CAP_ + c];
    const float4 x = *(const float4*)(h + (size_t)t * D_ + c4);
    const float f[4] = {x.x, x.y, x.z, x.w};
    unsigned hu[4], lu[4];
    #pragma unroll
    for (int j = 0; j < 4; ++j) {
      const unsigned u = __float_as_uint(f[j]);
      const float lo = f[j] - __uint_as_float(u & 0xFFFF0000u);
      hu[j] = u; lu[j] = __float_as_uint(lo);
    }
    uint2 hp, lp;
    hp.x = pack_hi2(hu[0], hu[1]); hp.y = pack_hi2(hu[2], hu[3]);
    lp.x = pack_hi2(lu[0], lu[1]); lp.y = pack_hi2(lu[2], lu[3]);
    *(uint2*)(dst + c4) = hp;
    *(uint2*)(dst + D_ + c4) = lp;
  } else {
    uint2 z; z.x = 0u; z.y = 0u;
    *(uint2*)(dst + c4) = z;
    *(uint2*)(dst + D_ + c4) = z;
  }
}

// ================================================================ weight convert: W [K][N] f32 -> W'^T [N][2K] bf16
__global__ __launch_bounds__(256) void convw_kernel(
    const float* __restrict__ W, unsigned short* __restrict__ out, int K, int N)
{
  const float* Wp = W + (size_t)blockIdx.z * K * N;
  unsigned short* op = out + (size_t)blockIdx.z * N * 2 * K;
  const int k0 = blockIdx.y * 64, n0 = blockIdx.x * 64;
  __shared__ float tile[64][65];
  const int tr = threadIdx.x >> 6;
  const int tc = threadIdx.x & 63;
  #pragma unroll
  for (int it = 0; it < 16; ++it) {
    const int r = it * 4 + tr;
    tile[r][tc] = Wp[(size_t)(k0 + r) * N + n0 + tc];
  }
  __syncthreads();
  #pragma unroll
  for (int it = 0; it < 16; ++it) {
    const int n = it * 4 + tr;
    const float f = tile[tc][n];
    const unsigned u = __float_as_uint(f);
    const float lo = f - __uint_as_float(u & 0xFFFF0000u);
    op[(size_t)(n0 + n) * 2 * K + k0 + tc] = (unsigned short)(u >> 16);
    op[(size_t)(n0 + n) * 2 * K + K + k0 + tc] = (unsigned short)(__float_as_uint(lo) >> 16);
  }
}

// ================================================================ bf16 MFMA GEMM (m97-style)
// A: [M][2K] bf16 (hi|lo), B: [N][2K] bf16 (hi|lo).
// Virtual K' = 3K; per k-chunk of 64 the phases are (hi.hi, hi.lo, lo.hi).
// EPI 0: f32 store; 1: gelu -> split-bf16 [M][2N]; 2: f32 atomicAdd (split-K).
template <int EPI>
__device__ __forceinline__ void gemm_bf16_core(
    const unsigned short* __restrict__ A, const unsigned short* __restrict__ B,
    void* __restrict__ Cv, int N, int K, int vt0, int nvt)
{
  __shared__ unsigned short As[128 * 64];
  __shared__ unsigned short Bs[128 * 64];

  const int tid = threadIdx.x;
  const int lane = tid & 63;
  const int w = tid >> 6;
  const int wm = w >> 1, wn = w & 1;
  const int quad = lane >> 4, l15 = lane & 15;
  const int m0 = blockIdx.y * 128, n0 = blockIdx.x * 128;
  const size_t K2 = (size_t)2 * K;

  f32x4v acc[4][4];
  #pragma unroll
  for (int i = 0; i < 4; ++i)
    #pragma unroll
    for (int j = 0; j < 4; ++j) { acc[i][j][0] = 0.f; acc[i][j][1] = 0.f; acc[i][j][2] = 0.f; acc[i][j][3] = 0.f; }

  const int r0 = tid >> 3;          // staged row (0..31) per chunk-quarter
  const int c0 = (tid & 7) * 8;     // short offset within 64-short row

  for (int vt = vt0; vt < vt0 + nvt; ++vt) {
    const int kk = vt / 3;
    const int ph = vt - kk * 3;
    const int ka = kk * 64 + (ph == 2 ? K : 0);
    const int kb = kk * 64 + (ph == 1 ? K : 0);
    __syncthreads();
    const unsigned short* Ag = A + (size_t)(m0 + r0) * K2 + ka + c0;
    const unsigned short* Bg = B + (size_t)(n0 + r0) * K2 + kb + c0;
    #pragma unroll
    for (int i = 0; i < 4; ++i)
      lds_load16(Ag + (size_t)(i * 32) * K2, &As[(tid + i * 256) * 8]);
    #pragma unroll
    for (int i = 0; i < 4; ++i)
      lds_load16(Bg + (size_t)(i * 32) * K2, &Bs[(tid + i * 256) * 8]);
    __syncthreads();
    #pragma unroll
    for (int ks = 0; ks < 2; ++ks) {
      FragU fa[4], fb[4];
      #pragma unroll
      for (int i = 0; i < 4; ++i) {
        const unsigned short* pa = &As[(wm * 64 + i * 16 + l15) * 64 + ks * 32 + quad * 8];
        fa[i].u2[0] = *(const uint2*)pa; fa[i].u2[1] = *(const uint2*)(pa + 4);
      }
      #pragma unroll
      for (int j = 0; j < 4; ++j) {
        const unsigned short* pb = &Bs[(wn * 64 + j * 16 + l15) * 64 + ks * 32 + quad * 8];
        fb[j].u2[0] = *(const uint2*)pb; fb[j].u2[1] = *(const uint2*)(pb + 4);
      }
      #pragma unroll
      for (int i = 0; i < 4; ++i)
        #pragma unroll
        for (int j = 0; j < 4; ++j)
          acc[i][j] = __builtin_amdgcn_mfma_f32_16x16x32_bf16(fa[i].v, fb[j].v, acc[i][j], 0, 0, 0);
    }
  }

  #pragma unroll
  for (int i = 0; i < 4; ++i)
    #pragma unroll
    for (int j = 0; j < 4; ++j) {
      const int n = n0 + wn * 64 + j * 16 + l15;
      #pragma unroll
      for (int r = 0; r < 4; ++r) {
        const int m = m0 + wm * 64 + i * 16 + quad * 4 + r;
        const float v = acc[i][j][r];
        if (EPI == 0) {
          ((float*)Cv)[(size_t)m * N + n] = v;
        } else if (EPI == 2) {
          atomicAdd(&((float*)Cv)[(size_t)m * N + n], v);
        } else {
          const float gv = gelu_tanh(v);
          const unsigned u = __float_as_uint(gv);
          const float lo = gv - __uint_as_float(u & 0xFFFF0000u);
          unsigned short* C = (unsigned short*)Cv;
          C[(size_t)m * 2 * N + n] = (unsigned short)(u >> 16);
          C[(size_t)m * 2 * N + N + n] = (unsigned short)(__float_as_uint(lo) >> 16);
        }
      }
    }
}

template <int EPI, int SK>
__global__ __launch_bounds__(256, 2) void gemm_bf16_k(
    const unsigned short* __restrict__ Ab, const unsigned short* __restrict__ Bb,
    void* __restrict__ Cb, int N, int K, long sA, long sB, long sC)
{
  const int z = blockIdx.z;
  const int g = z / SK, sp = z - g * SK;
  const unsigned short* A = Ab + (size_t)g * sA;
  const unsigned short* B = Bb + (size_t)g * sB;
  void* C;
  if (EPI == 1) C = (void*)((unsigned short*)Cb + (size_t)g * sC);
  else          C = (void*)((float*)Cb + (size_t)g * sC);
  const int kps = K / 64;
  const int per = 3 * kps / SK;
  gemm_bf16_core<EPI>(A, B, C, N, K, sp * per, per);
}

__global__ __launch_bounds__(256, 2) void gemm_qkv_bf16(
    const unsigned short* __restrict__ xinp,
    const unsigned short* __restrict__ wqp, const unsigned short* __restrict__ wkp,
    const unsigned short* __restrict__ wvp,
    float* __restrict__ qb, float* __restrict__ kb, float* __restrict__ vb)
{
  const int z = blockIdx.z;
  const int g = z & 3;
  const int which = z >> 2;
  const unsigned short* A = xinp + (size_t)(2 * g) * CAP_ * 2 * D_;   // attn expert e=2g
  const unsigned short* B = ((which == 0) ? wqp : (which == 1) ? wkp : wvp) + (size_t)g * D_ * 2 * D_;
  float* C = ((which == 0) ? qb : (which == 1) ? kb : vb) + (size_t)g * CAP_ * D_;
  gemm_bf16_core<0>(A, B, (void*)C, D_, D_, 0, 48);
}

// ================================================================ RoPE
__global__ __launch_bounds__(256) void rope_kernel(
    float* __restrict__ q, float* __restrict__ k,
    const int* __restrict__ idx, const int* __restrict__ cnt)
{
  const int c = blockIdx.x, g = blockIdx.y;
  const int e = 2 * g;
  if (c >= cnt[e]) return;
  const int t = idx[e * CAP_ + c];
  const int tid = threadIdx.x;
  const int hh = tid >> 4;
  const int pp = tid & 15;
  const size_t base = ((size_t)g * CAP_ + c) * D_ + hh * DH_;
  const float tf = (float)t;
  #pragma unroll
  for (int u = 0; u < 2; ++u) {
    const int i = pp * 2 + u;
    const float invf = (float)::pow(10000.0, -(double)i / 32.0);
    const float ang = tf * invf;
    const float cs = (float)::cos((double)ang);
    const float sn = (float)::sin((double)ang);
    const float q0 = q[base + i], q1 = q[base + i + 32];
    q[base + i]      = q0 * cs - q1 * sn;
    q[base + i + 32] = q1 * cs + q0 * sn;
    const float k0 = k[base + i], k1 = k[base + i + 32];
    k[base + i]      = k0 * cs - k1 * sn;
    k[base + i + 32] = k1 * cs + k0 * sn;
  }
}

// ================================================================ MFMA flash attention
#define FBQ 128
#define LDK 68   // shorts per K/V^T/P LDS row
#define LDQ 72   // f32 per Q staging row

__global__ __launch_bounds__(256, 2) void flash_mfma(
    const float* __restrict__ qg, const float* __restrict__ kg,
    const float* __restrict__ vg, unsigned short* __restrict__ og)
{
  const int g = blockIdx.z, hh = blockIdx.y, qt = blockIdx.x;
  const size_t base = (size_t)g * CAP_ * D_ + hh * DH_;
  const float* Q = qg + base;
  const float* Kp = kg + base;
  const float* Vp = vg + base;
  unsigned short* Ob = og + (size_t)g * CAP_ * 2 * D_ + hh * DH_;

  __shared__ __align__(16) char lds_raw[69632];
  unsigned short* Kh  = (unsigned short*)lds_raw;
  unsigned short* Kl  = Kh  + 64 * LDK;
  unsigned short* Vth = Kl  + 64 * LDK;
  unsigned short* Vtl = Vth + 64 * LDK;
  unsigned short* Ph  = Vtl + 64 * LDK;
  unsigned short* Pl  = Ph  + FBQ * LDK;
  float* Qs = (float*)lds_raw;

  const int tid = threadIdx.x;
  const int lane = tid & 63;
  const int w = tid >> 6;
  const int quad = lane >> 4;
  const int l15 = lane & 15;

  #pragma unroll
  for (int it = 0; it < 8; ++it) {
    const int row = it * 16 + (tid >> 4);
    const int c4 = (tid & 15) * 4;
    *(float4*)&Qs[row * LDQ + c4] = *(const float4*)(Q + (size_t)(qt * FBQ + row) * D_ + c4);
  }
  __syncthreads();
  FragU qf[2][2][2];
  #pragma unroll
  for (int rs = 0; rs < 2; ++rs)
    #pragma unroll
    for (int ks = 0; ks < 2; ++ks) {
      const float* p0 = &Qs[(w * 32 + rs * 16 + l15) * LDQ + ks * 32 + quad * 8];
      const float4 f0 = *(const float4*)p0;
      const float4 f1 = *(const float4*)(p0 + 4);
      split8(f0, f1, qf[rs][ks][0], qf[rs][ks][1]);
    }
  __syncthreads();

  f32x4v acc[2][4];
  float m_r[2][4], l_r[2][4];
  #pragma unroll
  for (int rs = 0; rs < 2; ++rs)
    #pragma unroll
    for (int r = 0; r < 4; ++r) { m_r[rs][r] = -1e30f; l_r[rs][r] = 0.0f; }
  #pragma unroll
  for (int rs = 0; rs < 2; ++rs)
    #pragma unroll
    for (int dt = 0; dt < 4; ++dt) { acc[rs][dt][0] = 0.f; acc[rs][dt][1] = 0.f; acc[rs][dt][2] = 0.f; acc[rs][dt][3] = 0.f; }

  for (int kt = 0; kt < 16; ++kt) {
    __syncthreads();
    #pragma unroll
    for (int it = 0; it < 4; ++it) {
      const int r = it * 16 + (tid >> 4);
      const int c4 = (tid & 15) * 4;
      const float4 kv = *(const float4*)(Kp + (size_t)(kt * 64 + r) * D_ + c4);
      {
        const unsigned u0 = __float_as_uint(kv.x), u1 = __float_as_uint(kv.y);
        const unsigned u2 = __float_as_uint(kv.z), u3 = __float_as_uint(kv.w);
        const float l0 = kv.x - __uint_as_float(u0 & 0xFFFF0000u);
        const float l1 = kv.y - __uint_as_float(u1 & 0xFFFF0000u);
        const float l2 = kv.z - __uint_as_float(u2 & 0xFFFF0000u);
        const float l3 = kv.w - __uint_as_float(u3 & 0xFFFF0000u);
        uint2 hp, lp;
        hp.x = pack_hi2(u0, u1); hp.y = pack_hi2(u2, u3);
        lp.x = pack_hi2(__float_as_uint(l0), __float_as_uint(l1));
        lp.y = pack_hi2(__float_as_uint(l2), __float_as_uint(l3));
        *(uint2*)&Kh[r * LDK + c4] = hp;
        *(uint2*)&Kl[r * LDK + c4] = lp;
      }
      const float4 vv = *(const float4*)(Vp + (size_t)(kt * 64 + r) * D_ + c4);
      const float vf[4] = {vv.x, vv.y, vv.z, vv.w};
      #pragma unroll
      for (int u = 0; u < 4; ++u) {
        const unsigned uu = __float_as_uint(vf[u]);
        const float lo = vf[u] - __uint_as_float(uu & 0xFFFF0000u);
        Vth[(c4 + u) * LDK + r] = (unsigned short)(uu >> 16);
        Vtl[(c4 + u) * LDK + r] = (unsigned short)(__float_as_uint(lo) >> 16);
      }
    }
    __syncthreads();
    f32x4v sfr[2][4];
    #pragma unroll
    for (int rs = 0; rs < 2; ++rs)
      #pragma unroll
      for (int j = 0; j < 4; ++j) {
        f32x4v s; s[0] = 0.f; s[1] = 0.f; s[2] = 0.f; s[3] = 0.f;
        #pragma unroll
        for (int ks = 0; ks < 2; ++ks) {
          FragU kh, kl;
          const unsigned short* pk = &Kh[(j * 16 + l15) * LDK + ks * 32 + quad * 8];
          const unsigned short* pl = &Kl[(j * 16 + l15) * LDK + ks * 32 + quad * 8];
          kh.u2[0] = *(const uint2*)pk; kh.u2[1] = *(const uint2*)(pk + 4);
          kl.u2[0] = *(const uint2*)pl; kl.u2[1] = *(const uint2*)(pl + 4);
          s = __builtin_amdgcn_mfma_f32_16x16x32_bf16(qf[rs][ks][0].v, kh.v, s, 0, 0, 0);
          s = __builtin_amdgcn_mfma_f32_16x16x32_bf16(qf[rs][ks][0].v, kl.v, s, 0, 0, 0);
          s = __builtin_amdgcn_mfma_f32_16x16x32_bf16(qf[rs][ks][1].v, kh.v, s, 0, 0, 0);
        }
        sfr[rs][j] = s;
      }
    #pragma unroll
    for (int rs = 0; rs < 2; ++rs) {
      #pragma unroll
      for (int r = 0; r < 4; ++r) {
        float s0 = sfr[rs][0][r] * 0.125f;
        float s1 = sfr[rs][1][r] * 0.125f;
        float s2 = sfr[rs][2][r] * 0.125f;
        float s3 = sfr[rs][3][r] * 0.125f;
        float mx = fmaxf(fmaxf(s0, s1), fmaxf(s2, s3));
        #pragma unroll
        for (int o = 1; o < 16; o <<= 1) mx = fmaxf(mx, __shfl_xor(mx, o));
        const float nm = fmaxf(m_r[rs][r], mx);
        const float al = __expf(m_r[rs][r] - nm);
        m_r[rs][r] = nm;
        const float p0 = __expf(s0 - nm);
        const float p1 = __expf(s1 - nm);
        const float p2 = __expf(s2 - nm);
        const float p3 = __expf(s3 - nm);
        float rsum = p0 + p1 + p2 + p3;
        #pragma unroll
        for (int o = 1; o < 16; o <<= 1) rsum += __shfl_xor(rsum, o);
        l_r[rs][r] = l_r[rs][r] * al + rsum;
        #pragma unroll
        for (int dt = 0; dt < 4; ++dt) acc[rs][dt][r] *= al;
        const int row = w * 32 + rs * 16 + quad * 4 + r;
        const float pv[4] = {p0, p1, p2, p3};
        #pragma unroll
        for (int j = 0; j < 4; ++j) {
          const unsigned u = __float_as_uint(pv[j]);
          const float lo = pv[j] - __uint_as_float(u & 0xFFFF0000u);
          Ph[row * LDK + j * 16 + l15] = (unsigned short)(u >> 16);
          Pl[row * LDK + j * 16 + l15] = (unsigned short)(__float_as_uint(lo) >> 16);
        }
      }
    }
    __syncthreads();
    FragU pf[2][2][2];
    #pragma unroll
    for (int rs = 0; rs < 2; ++rs)
      #pragma unroll
      for (int ks = 0; ks < 2; ++ks) {
        const unsigned short* ph = &Ph[(w * 32 + rs * 16 + l15) * LDK + ks * 32 + quad * 8];
        const unsigned short* pl = &Pl[(w * 32 + rs * 16 + l15) * LDK + ks * 32 + quad * 8];
        pf[rs][ks][0].u2[0] = *(const uint2*)ph; pf[rs][ks][0].u2[1] = *(const uint2*)(ph + 4);
        pf[rs][ks][1].u2[0] = *(const uint2*)pl; pf[rs][ks][1].u2[1] = *(const uint2*)(pl + 4);
      }
    #pragma unroll
    for (int dt = 0; dt < 4; ++dt)
      #pragma unroll
      for (int ks = 0; ks < 2; ++ks) {
        FragU vh, vl;
        const unsigned short* pv_ = &Vth[(dt * 16 + l15) * LDK + ks * 32 + quad * 8];
        const unsigned short* pl_ = &Vtl[(dt * 16 + l15) * LDK + ks * 32 + quad * 8];
        vh.u2[0] = *(const uint2*)pv_; vh.u2[1] = *(const uint2*)(pv_ + 4);
        vl.u2[0] = *(const uint2*)pl_; vl.u2[1] = *(const uint2*)(pl_ + 4);
        #pragma unroll
        for (int rs = 0; rs < 2; ++rs) {
          acc[rs][dt] = __builtin_amdgcn_mfma_f32_16x16x32_bf16(pf[rs][ks][0].v, vh.v, acc[rs][dt], 0, 0, 0);
          acc[rs][dt] = __builtin_amdgcn_mfma_f32_16x16x32_bf16(pf[rs][ks][0].v, vl.v, acc[rs][dt], 0, 0, 0);
          acc[rs][dt] = __builtin_amdgcn_mfma_f32_16x16x32_bf16(pf[rs][ks][1].v, vh.v, acc[rs][dt], 0, 0, 0);
        }
      }
  }
  // ---- epilogue: write split-bf16 ao' [CAP][2*D]
  #pragma unroll
  for (int rs = 0; rs < 2; ++rs)
    #pragma unroll
    for (int r = 0; r < 4; ++r) {
      const float inv = 1.0f / l_r[rs][r];
      const int row = qt * FBQ + w * 32 + rs * 16 + quad * 4 + r;
      #pragma unroll
      for (int dt = 0; dt < 4; ++dt) {
        const float v = acc[rs][dt][r] * inv;
        const unsigned u = __float_as_uint(v);
        const float lo = v - __uint_as_float(u & 0xFFFF0000u);
        Ob[(size_t)row * 2 * D_ + dt * 16 + l15] = (unsigned short)(u >> 16);
        Ob[(size_t)row * 2 * D_ + D_ + dt * 16 + l15] = (unsigned short)(__float_as_uint(lo) >> 16);
      }
    }
}

// ================================================================ hnew = h*(1-rho)
__global__ __launch_bounds__(256) void initnew_kernel(
    const float* __restrict__ h, const float* __restrict__ rho, float* __restrict__ hn)
{
  const int t = blockIdx.x;
  const float f = 1.0f - rho[t];
  const int c = threadIdx.x * 4;
  float4 x = *(const float4*)(h + (size_t)t * D_ + c);
  x.x *= f; x.y *= f; x.z *= f; x.w *= f;
  *(float4*)(hn + (size_t)t * D_ + c) = x;
}

// ================================================================ scatter
__global__ __launch_bounds__(256) void scatter_kernel(
    const float* __restrict__ eo, const int* __restrict__ idx, const int* __restrict__ cnt,
    const float* __restrict__ probs, float* __restrict__ hn)
{
  const int c = blockIdx.x, e = blockIdx.y;
  if (c >= cnt[e]) return;
  const int t = idx[e * CAP_ + c];
  const float w = probs[t * 8 + e];
  const float* src = eo + ((size_t)e * CAP_ + c) * D_;
  float* dst = hn + (size_t)t * D_;
  const int c4 = threadIdx.x * 4;
  #pragma unroll
  for (int j = 0; j < 4; ++j) atomicAdd(dst + c4 + j, src[c4 + j] * w);
}

// ================================================================ RMS norm
__global__ __launch_bounds__(256) void rms_kernel(
    const float* __restrict__ h, const float* __restrict__ w, float* __restrict__ out)
{
  const int t = blockIdx.x;
  const int c = threadIdx.x * 4;
  const float4 x = *(const float4*)(h + (size_t)t * D_ + c);
  float ss = x.x * x.x + x.y * x.y + x.z * x.z + x.w * x.w;
  #pragma unroll
  for (int off = 32; off > 0; off >>= 1) ss += __shfl_down(ss, off);
  __shared__ float wsum[4];
  __shared__ float sscale;
  const int lane = threadIdx.x & 63, wv = threadIdx.x >> 6;
  if (lane == 0) wsum[wv] = ss;
  __syncthreads();
  if (threadIdx.x == 0) {
    const float s = wsum[0] + wsum[1] + wsum[2] + wsum[3];
    sscale = 1.0f / sqrtf(s * (1.0f / (float)D_) + 1e-6f);
  }
  __syncthreads();
  const float sc = sscale;
  const float4 w4 = *(const float4*)(w + c);
  float4 o;
  o.x = x.x * sc * w4.x; o.y = x.y * sc * w4.y; o.z = x.z * sc * w4.z; o.w = x.w * sc * w4.w;
  *(float4*)(out + (size_t)t * D_ + c) = o;
}

// ================================================================ host
extern "C" void kernel_launch(void* const* d_in, const int* in_sizes, int n_in,
                              void* d_out, int out_size, void* d_ws, size_t ws_size,
                              hipStream_t stream)
{
  (void)in_sizes; (void)n_in; (void)out_size; (void)ws_size;
  const int* ids = (const int*)d_in[0];
  const float* embed_w = (const float*)d_in[1];
  const float* router_w = (const float*)d_in[2];
  const float* wq = (const float*)d_in[3];
  const float* wk = (const float*)d_in[4];
  const float* wv = (const float*)d_in[5];
  const float* wo = (const float*)d_in[6];
  const float* w1 = (const float*)d_in[7];
  const float* w2 = (const float*)d_in[8];
  const float* lnw = (const float*)d_in[9];
  float* out = (float*)d_out;

  float* p = (float*)d_ws;
  const size_t TD = (size_t)T_ * D_;
  float* hA = p;    p += TD;
  float* hB = p;    p += TD;
  float* probs = p; p += (size_t)T_ * E_;
  float* gmask = p; p += (size_t)E_ * T_;
  float* rho = p;   p += T_;
  int* idx = (int*)p;   p += E_ * CAP_;
  int* cnt = (int*)p;   p += 16;
  float* eo = p;   p += (size_t)E_ * CAP_ * D_;
  // qb|kb|vb|aob form a contiguous 64 MB region that mid' aliases after O-proj.
  float* qb = p;   p += (size_t)4 * CAP_ * D_;
  float* kb = p;   p += (size_t)4 * CAP_ * D_;
  float* vb = p;   p += (size_t)4 * CAP_ * D_;
  unsigned short* aob = (unsigned short*)p; p += (size_t)4 * CAP_ * D_;  // 4*CAP*2D shorts
  unsigned short* midp = (unsigned short*)qb;                            // 4*CAP*2*MLP shorts (alias)
  unsigned short* xinp = (unsigned short*)p; p += (size_t)E_ * CAP_ * D_; // E*CAP*2D shorts
  unsigned short* wqp = (unsigned short*)p; p += (size_t)4 * D_ * D_;    // [N=D][2K=2D] x4
  unsigned short* wkp = (unsigned short*)p; p += (size_t)4 * D_ * D_;
  unsigned short* wvp = (unsigned short*)p; p += (size_t)4 * D_ * D_;
  unsigned short* wop = (unsigned short*)p; p += (size_t)4 * D_ * D_;
  unsigned short* w1p = (unsigned short*)p; p += (size_t)4 * D_ * MLP_;  // [N=MLP][2K=2D] x4
  unsigned short* w2p = (unsigned short*)p; p += (size_t)4 * D_ * MLP_;  // [N=D][2K=2MLP] x4

  // one-time weight split/transpose (bf16 hi|lo, B^T layout)
  convw_kernel<<<dim3(D_ / 64, D_ / 64, 4), 256, 0, stream>>>(wq, wqp, D_, D_);
  convw_kernel<<<dim3(D_ / 64, D_ / 64, 4), 256, 0, stream>>>(wk, wkp, D_, D_);
  convw_kernel<<<dim3(D_ / 64, D_ / 64, 4), 256, 0, stream>>>(wv, wvp, D_, D_);
  convw_kernel<<<dim3(D_ / 64, D_ / 64, 4), 256, 0, stream>>>(wo, wop, D_, D_);
  convw_kernel<<<dim3(MLP_ / 64, D_ / 64, 4), 256, 0, stream>>>(w1, w1p, D_, MLP_);
  convw_kernel<<<dim3(D_ / 64, MLP_ / 64, 4), 256, 0, stream>>>(w2, w2p, MLP_, D_);

  embed_kernel<<<T_, 256, 0, stream>>>(ids, embed_w, hA);
  float* cur = hA;
  float* nxt = hB;
  for (int hop = 0; hop < HOPS_; ++hop) {
    router_kernel<<<T_, 64, 0, stream>>>(cur, router_w + (size_t)hop * 9 * D_, probs, gmask);
    zero_kernel<<<16, 256, 0, stream>>>(rho, cnt);
    select_kernel<<<dim3(16, 8), 256, 0, stream>>>(gmask, probs, idx, cnt, rho);
    gather_kernel<<<dim3(CAP_, E_), 256, 0, stream>>>(cur, idx, cnt, xinp);
    gemm_qkv_bf16<<<dim3(D_ / 128, CAP_ / 128, 12), 256, 0, stream>>>(xinp, wqp, wkp, wvp, qb, kb, vb);
    rope_kernel<<<dim3(CAP_, 4), 256, 0, stream>>>(qb, kb, idx, cnt);
    flash_mfma<<<dim3(CAP_ / FBQ, 16, 4), 256, 0, stream>>>(qb, kb, vb, aob);
    zeroeo_kernel<<<8192, 256, 0, stream>>>(eo);
    // O-proj: split-K=4, atomic accumulate into eo (attn experts)
    gemm_bf16_k<2, 4><<<dim3(D_ / 128, CAP_ / 128, 16), 256, 0, stream>>>(
        aob, wop, (void*)eo, D_, D_,
        (long)CAP_ * 2 * D_, (long)D_ * 2 * D_, (long)2 * CAP_ * D_);
    // FFN w1 (gelu epilogue -> split-bf16 mid'); mid' aliases qb..aob, so launch after O-proj.
    gemm_bf16_k<1, 1><<<dim3(MLP_ / 128, CAP_ / 128, 4), 256, 0, stream>>>(
        xinp + (size_t)CAP_ * 2 * D_, w1p, (void*)midp, MLP_, D_,
        (long)2 * CAP_ * 2 * D_, (long)MLP_ * 2 * D_, (long)CAP_ * 2 * MLP_);
    // FFN w2: split-K=4, atomic accumulate into eo (ffn experts)
    gemm_bf16_k<2, 4><<<dim3(D_ / 128, CAP_ / 128, 16), 256, 0, stream>>>(
        midp, w2p, (void*)(eo + (size_t)CAP_ * D_), D_, MLP_,
        (long)CAP_ * 2 * MLP_, (long)D_ * 2 * MLP_, (long)2 * CAP_ * D_);
    initnew_kernel<<<T_, 256, 0, stream>>>(cur, rho, nxt);
    scatter_kernel<<<dim3(CAP_, E_), 256, 0, stream>>>(eo, idx, cnt, probs, nxt);
    float* tmp = cur; cur = nxt; nxt = tmp;
  }
  rms_kernel<<<T_, 256, 0, stream>>>(cur, lnw, out);
}

// Round 2
// 2724.320 us; speedup vs baseline: 1.2272x; 1.2272x over previous
//
#include <hip/hip_runtime.h>
#include <math.h>

#define T_ 4096
#define D_ 1024
#define H_ 16
#define DH_ 64
#define E_ 8
#define CAP_ 1024
#define MLP_ 4096
#define HOPS_ 3

// ================================================================ embed
__global__ __launch_bounds__(256) void embed_kernel(
    const int* __restrict__ ids, const float* __restrict__ ew, float* __restrict__ h)
{
  const int t = blockIdx.x;
  const int id = ids[t];
  const int c = threadIdx.x * 4;
  *(float4*)(h + (size_t)t * D_ + c) = *(const float4*)(ew + (size_t)id * D_ + c);
}

// ================================================================ router
__global__ __launch_bounds__(64) void router_kernel(
    const float* __restrict__ h, const float* __restrict__ rw,
    float* __restrict__ probs, float* __restrict__ gmask)
{
  const int t = blockIdx.x;
  const int lane = threadIdx.x;
  __shared__ float hs[D_];
  #pragma unroll
  for (int j = 0; j < 4; ++j)
    *(float4*)&hs[lane * 4 + j * 256] = *(const float4*)(h + (size_t)t * D_ + lane * 4 + j * 256);
  __syncthreads();
  float l9[9];
  #pragma unroll
  for (int e = 0; e < 9; ++e) {
    float s = 0.0f;
    for (int i = lane; i < D_; i += 64) s += hs[i] * rw[e * D_ + i];
    #pragma unroll
    for (int off = 32; off > 0; off >>= 1) s += __shfl_down(s, off);
    l9[e] = s;
  }
  if (lane == 0) {
    float m = l9[0];
    #pragma unroll
    for (int e = 1; e < 9; ++e) m = fmaxf(m, l9[e]);
    float sum = 0.0f;
    float ex[9];
    #pragma unroll
    for (int e = 0; e < 9; ++e) { ex[e] = expf(l9[e] - m); sum += ex[e]; }
    const float inv = 1.0f / sum;
    int b1 = 0;
    #pragma unroll
    for (int e = 1; e < 9; ++e) if (l9[e] > l9[b1]) b1 = e;
    int b2 = (b1 == 0) ? 1 : 0;
    #pragma unroll
    for (int e = 0; e < 9; ++e) if (e != b1 && e != b2 && l9[e] > l9[b2]) b2 = e;
    #pragma unroll
    for (int e = 0; e < 8; ++e) {
      const float pe = ex[e] * inv;
      probs[t * 8 + e] = pe;
      gmask[(size_t)e * T_ + t] = (e == b1 || e == b2) ? pe : -1e30f;
    }
  }
}

// ================================================================ zero
__global__ __launch_bounds__(256) void zero_kernel(float* __restrict__ rho, int* __restrict__ cnt)
{
  const int i = blockIdx.x * 256 + threadIdx.x;
  if (i < T_) rho[i] = 0.0f;
  if (i < E_) cnt[i] = 0;
}

__global__ __launch_bounds__(256) void zeroeo_kernel(float* __restrict__ eo)
{
  const size_t i = ((size_t)blockIdx.x * 256 + threadIdx.x) * 4;
  float4 z; z.x = z.y = z.z = z.w = 0.0f;
  *(float4*)(eo + i) = z;
}

// ================================================================ capacity select (rank-based)
__global__ __launch_bounds__(256) void select_kernel(
    const float* __restrict__ gmask, const float* __restrict__ probs,
    int* __restrict__ idx, int* __restrict__ cnt, float* __restrict__ rho)
{
  __shared__ float row[T_];
  const int e = blockIdx.y;
  const int tid = threadIdx.x;
  const float* gr = gmask + (size_t)e * T_;
  #pragma unroll
  for (int j = 0; j < 16; ++j) row[tid + 256 * j] = gr[tid + 256 * j];
  __syncthreads();
  const int t = blockIdx.x * 256 + tid;
  const float g = row[t];
  if (g > -1e29f) {
    int rank = 0;
    for (int tt = 0; tt < T_; ++tt) {
      const float gg = row[tt];
      rank += (gg > g) || (gg == g && tt < t);
    }
    if (rank < CAP_) {
      const int pos = atomicAdd(&cnt[e], 1);
      idx[e * CAP_ + pos] = t;
      atomicAdd(&rho[t], probs[t * 8 + e]);
    }
  }
}

// ================================================================ bf16 helpers
typedef __bf16 bf16x8 __attribute__((ext_vector_type(8)));
typedef float f32x4v __attribute__((ext_vector_type(4)));

union FragU { uint2 u2[2]; bf16x8 v; };

__device__ __forceinline__ unsigned pack_hi2(unsigned u0, unsigned u1)
{
  return (u0 >> 16) | (u1 & 0xFFFF0000u);
}

__device__ __forceinline__ void split8(const float4 a, const float4 b, FragU& h, FragU& l)
{
  const float f[8] = {a.x, a.y, a.z, a.w, b.x, b.y, b.z, b.w};
  unsigned hu[8], lu[8];
  #pragma unroll
  for (int i = 0; i < 8; ++i) {
    const unsigned u = __float_as_uint(f[i]);
    const float lo = f[i] - __uint_as_float(u & 0xFFFF0000u);
    hu[i] = u; lu[i] = __float_as_uint(lo);
  }
  h.u2[0].x = pack_hi2(hu[0], hu[1]); h.u2[0].y = pack_hi2(hu[2], hu[3]);
  h.u2[1].x = pack_hi2(hu[4], hu[5]); h.u2[1].y = pack_hi2(hu[6], hu[7]);
  l.u2[0].x = pack_hi2(lu[0], lu[1]); l.u2[0].y = pack_hi2(lu[2], lu[3]);
  l.u2[1].x = pack_hi2(lu[4], lu[5]); l.u2[1].y = pack_hi2(lu[6], lu[7]);
}

__device__ __forceinline__ void lds_load16(const void* g, void* l)
{
  __builtin_amdgcn_global_load_lds(
      (const __attribute__((address_space(1))) unsigned int*)g,
      (__attribute__((address_space(3))) unsigned int*)l, 16, 0, 0);
}

__device__ __forceinline__ float gelu_tanh(float x)
{
  const float x3 = x * x * x;
  return 0.5f * x * (1.0f + tanhf(0.7978845608028654f * (x + 0.044715f * x3)));
}

// ================================================================ gather (writes split-bf16 xin')
// xin' layout per row: [2*D_] shorts, hi at [0,D), lo at [D,2D)
__global__ __launch_bounds__(256) void gather_kernel(
    const float* __restrict__ h, const int* __restrict__ idx, const int* __restrict__ cnt,
    unsigned short* __restrict__ xinp)
{
  const int c = blockIdx.x, e = blockIdx.y;
  const int c4 = threadIdx.x * 4;
  unsigned short* dst = xinp + ((size_t)e * CAP_ + c) * 2 * D_;
  if (c < cnt[e]) {
    const int t = idx[e * CAP_ + c];
    const float4 x = *(const float4*)(h + (size_t)t * D_ + c4);
    const float f[4] = {x.x, x.y, x.z, x.w};
    unsigned hu[4], lu[4];
    #pragma unroll
    for (int j = 0; j < 4; ++j) {
      const unsigned u = __float_as_uint(f[j]);
      const float lo = f[j] - __uint_as_float(u & 0xFFFF0000u);
      hu[j] = u; lu[j] = __float_as_uint(lo);
    }
    uint2 hp, lp;
    hp.x = pack_hi2(hu[0], hu[1]); hp.y = pack_hi2(hu[2], hu[3]);
    lp.x = pack_hi2(lu[0], lu[1]); lp.y = pack_hi2(lu[2], lu[3]);
    *(uint2*)(dst + c4) = hp;
    *(uint2*)(dst + D_ + c4) = lp;
  } else {
    uint2 z; z.x = 0u; z.y = 0u;
    *(uint2*)(dst + c4) = z;
    *(uint2*)(dst + D_ + c4) = z;
  }
}

// ================================================================ weight convert: W [K][N] f32 -> W'^T [N][2K] bf16
__global__ __launch_bounds__(256) void convw_kernel(
    const float* __restrict__ W, unsigned short* __restrict__ out, int K, int N)
{
  const float* Wp = W + (size_t)blockIdx.z * K * N;
  unsigned short* op = out + (size_t)blockIdx.z * N * 2 * K;
  const int k0 = blockIdx.y * 64, n0 = blockIdx.x * 64;
  __shared__ float tile[64][65];
  const int tr = threadIdx.x >> 6;
  const int tc = threadIdx.x & 63;
  #pragma unroll
  for (int it = 0; it < 16; ++it) {
    const int r = it * 4 + tr;
    tile[r][tc] = Wp[(size_t)(k0 + r) * N + n0 + tc];
  }
  __syncthreads();
  #pragma unroll
  for (int it = 0; it < 16; ++it) {
    const int n = it * 4 + tr;
    const float f = tile[tc][n];
    const unsigned u = __float_as_uint(f);
    const float lo = f - __uint_as_float(u & 0xFFFF0000u);
    op[(size_t)(n0 + n) * 2 * K + k0 + tc] = (unsigned short)(u >> 16);
    op[(size_t)(n0 + n) * 2 * K + K + k0 + tc] = (unsigned short)(__float_as_uint(lo) >> 16);
  }
}

// ================================================================ bf16 MFMA GEMM (split-bf16, single-stage per K-chunk)
// A: [M][2K] bf16 (hi|lo), B: [N][2K] bf16 (hi|lo).
// LDS rows: [hi(32) | lo(32)] shorts, chunk-XOR-swizzled by (row&7). One stage
// of 32 KB feeds 48 MFMAs (hi.hi, hi.lo, lo.hi).
// EPI 0: f32 store; 1: gelu -> split-bf16 [M][2N]; 2: f32 atomicAdd (split-K).
template <int EPI>
__device__ __forceinline__ void gemm_bf16_core(
    const unsigned short* __restrict__ A, const unsigned short* __restrict__ B,
    void* __restrict__ Cv, int N, int K, int kc0, int nkc, int m0, int n0)
{
  __shared__ unsigned short As[128 * 64];
  __shared__ unsigned short Bs[128 * 64];

  const int tid = threadIdx.x;
  const int lane = tid & 63;
  const int w = tid >> 6;
  const int wm = w >> 1, wn = w & 1;
  const int quad = lane >> 4, l15 = lane & 15;
  const size_t K2 = (size_t)2 * K;

  f32x4v acc[4][4];
  #pragma unroll
  for (int i = 0; i < 4; ++i)
    #pragma unroll
    for (int j = 0; j < 4; ++j) { acc[i][j][0] = 0.f; acc[i][j][1] = 0.f; acc[i][j][2] = 0.f; acc[i][j][3] = 0.f; }

  // staging: thread handles row r0+32i, physical chunk pc; source chunk pre-swizzled
  const int r0 = tid >> 3;
  const int pc = tid & 7;

  for (int kc = kc0; kc < kc0 + nkc; ++kc) {
    const int kb = kc * 32;
    __syncthreads();
    #pragma unroll
    for (int i = 0; i < 4; ++i) {
      const int row = r0 + i * 32;
      const int lc = pc ^ (row & 7);
      const int goff = (lc < 4) ? (kb + lc * 8) : (K + kb + (lc - 4) * 8);
      lds_load16(A + (size_t)(m0 + row) * K2 + goff, &As[(tid + i * 256) * 8]);
    }
    #pragma unroll
    for (int i = 0; i < 4; ++i) {
      const int row = r0 + i * 32;
      const int lc = pc ^ (row & 7);
      const int goff = (lc < 4) ? (kb + lc * 8) : (K + kb + (lc - 4) * 8);
      lds_load16(B + (size_t)(n0 + row) * K2 + goff, &Bs[(tid + i * 256) * 8]);
    }
    __syncthreads();

    FragU fah[4], fbh[4], fbl[4], fal[4];
    #pragma unroll
    for (int i = 0; i < 4; ++i) {
      const int row = wm * 64 + i * 16 + l15;
      const unsigned short* pr = &As[row * 64 + ((quad ^ (row & 7)) * 8)];
      fah[i].u2[0] = *(const uint2*)pr; fah[i].u2[1] = *(const uint2*)(pr + 4);
    }
    #pragma unroll
    for (int j = 0; j < 4; ++j) {
      const int row = wn * 64 + j * 16 + l15;
      const unsigned short* pr = &Bs[row * 64 + ((quad ^ (row & 7)) * 8)];
      fbh[j].u2[0] = *(const uint2*)pr; fbh[j].u2[1] = *(const uint2*)(pr + 4);
    }
    #pragma unroll
    for (int i = 0; i < 4; ++i)
      #pragma unroll
      for (int j = 0; j < 4; ++j)
        acc[i][j] = __builtin_amdgcn_mfma_f32_16x16x32_bf16(fah[i].v, fbh[j].v, acc[i][j], 0, 0, 0);
    #pragma unroll
    for (int j = 0; j < 4; ++j) {
      const int row = wn * 64 + j * 16 + l15;
      const unsigned short* pr = &Bs[row * 64 + (((quad + 4) ^ (row & 7)) * 8)];
      fbl[j].u2[0] = *(const uint2*)pr; fbl[j].u2[1] = *(const uint2*)(pr + 4);
    }
    #pragma unroll
    for (int i = 0; i < 4; ++i)
      #pragma unroll
      for (int j = 0; j < 4; ++j)
        acc[i][j] = __builtin_amdgcn_mfma_f32_16x16x32_bf16(fah[i].v, fbl[j].v, acc[i][j], 0, 0, 0);
    #pragma unroll
    for (int i = 0; i < 4; ++i) {
      const int row = wm * 64 + i * 16 + l15;
      const unsigned short* pr = &As[row * 64 + (((quad + 4) ^ (row & 7)) * 8)];
      fal[i].u2[0] = *(const uint2*)pr; fal[i].u2[1] = *(const uint2*)(pr + 4);
    }
    #pragma unroll
    for (int i = 0; i < 4; ++i)
      #pragma unroll
      for (int j = 0; j < 4; ++j)
        acc[i][j] = __builtin_amdgcn_mfma_f32_16x16x32_bf16(fal[i].v, fbh[j].v, acc[i][j], 0, 0, 0);
  }

  #pragma unroll
  for (int i = 0; i < 4; ++i)
    #pragma unroll
    for (int j = 0; j < 4; ++j) {
      const int n = n0 + wn * 64 + j * 16 + l15;
      #pragma unroll
      for (int r = 0; r < 4; ++r) {
        const int m = m0 + wm * 64 + i * 16 + quad * 4 + r;
        const float v = acc[i][j][r];
        if (EPI == 0) {
          ((float*)Cv)[(size_t)m * N + n] = v;
        } else if (EPI == 2) {
          atomicAdd(&((float*)Cv)[(size_t)m * N + n], v);
        } else {
          const float gv = gelu_tanh(v);
          const unsigned u = __float_as_uint(gv);
          const float lo = gv - __uint_as_float(u & 0xFFFF0000u);
          unsigned short* C = (unsigned short*)Cv;
          C[(size_t)m * 2 * N + n] = (unsigned short)(u >> 16);
          C[(size_t)m * 2 * N + N + n] = (unsigned short)(__float_as_uint(lo) >> 16);
        }
      }
    }
}

template <int EPI, int SK>
__global__ __launch_bounds__(256, 2) void gemm_bf16_k(
    const unsigned short* __restrict__ Ab, const unsigned short* __restrict__ Bb,
    void* __restrict__ Cb, int N, int K, long sA, long sB, long sC)
{
  // XCD-aware bijective block swizzle (total % 8 == 0 for all launches)
  const int nx = gridDim.x, ny = gridDim.y;
  const int total = nx * ny * gridDim.z;
  int flat = blockIdx.x + nx * (blockIdx.y + ny * blockIdx.z);
  int s = (flat & 7) * (total >> 3) + (flat >> 3);
  const int bx = s % nx; s /= nx;
  const int by = s % ny;
  const int z = s / ny;

  const int g = z / SK, sp = z - g * SK;
  const unsigned short* A = Ab + (size_t)g * sA;
  const unsigned short* B = Bb + (size_t)g * sB;
  void* C;
  if (EPI == 1) C = (void*)((unsigned short*)Cb + (size_t)g * sC);
  else          C = (void*)((float*)Cb + (size_t)g * sC);
  const int nkc = (K / 32) / SK;
  gemm_bf16_core<EPI>(A, B, C, N, K, sp * nkc, nkc, by * 128, bx * 128);
}

__global__ __launch_bounds__(256, 2) void gemm_qkv_bf16(
    const unsigned short* __restrict__ xinp,
    const unsigned short* __restrict__ wqp, const unsigned short* __restrict__ wkp,
    const unsigned short* __restrict__ wvp,
    float* __restrict__ qb, float* __restrict__ kb, float* __restrict__ vb)
{
  const int nx = gridDim.x, ny = gridDim.y;
  const int total = nx * ny * gridDim.z;
  int flat = blockIdx.x + nx * (blockIdx.y + ny * blockIdx.z);
  int s = (flat & 7) * (total >> 3) + (flat >> 3);
  const int bx = s % nx; s /= nx;
  const int by = s % ny;
  const int z = s / ny;

  const int g = z & 3;
  const int which = z >> 2;
  const unsigned short* A = xinp + (size_t)(2 * g) * CAP_ * 2 * D_;   // attn expert e=2g
  const unsigned short* B = ((which == 0) ? wqp : (which == 1) ? wkp : wvp) + (size_t)g * D_ * 2 * D_;
  float* C = ((which == 0) ? qb : (which == 1) ? kb : vb) + (size_t)g * CAP_ * D_;
  gemm_bf16_core<0>(A, B, (void*)C, D_, D_, 0, 32, by * 128, bx * 128);
}

// ================================================================ RoPE
__global__ __launch_bounds__(256) void rope_kernel(
    float* __restrict__ q, float* __restrict__ k,
    const int* __restrict__ idx, const int* __restrict__ cnt)
{
  const int c = blockIdx.x, g = blockIdx.y;
  const int e = 2 * g;
  if (c >= cnt[e]) return;
  const int t = idx[e * CAP_ + c];
  const int tid = threadIdx.x;
  const int hh = tid >> 4;
  const int pp = tid & 15;
  const size_t base = ((size_t)g * CAP_ + c) * D_ + hh * DH_;
  const float tf = (float)t;
  #pragma unroll
  for (int u = 0; u < 2; ++u) {
    const int i = pp * 2 + u;
    const float invf = (float)::pow(10000.0, -(double)i / 32.0);
    const float ang = tf * invf;
    const float cs = (float)::cos((double)ang);
    const float sn = (float)::sin((double)ang);
    const float q0 = q[base + i], q1 = q[base + i + 32];
    q[base + i]      = q0 * cs - q1 * sn;
    q[base + i + 32] = q1 * cs + q0 * sn;
    const float k0 = k[base + i], k1 = k[base + i + 32];
    k[base + i]      = k0 * cs - k1 * sn;
    k[base + i + 32] = k1 * cs + k0 * sn;
  }
}

// ================================================================ MFMA flash attention
#define FBQ 128
#define LDK 68   // shorts per K/V^T/P LDS row
#define LDQ 72   // f32 per Q staging row

__global__ __launch_bounds__(256, 2) void flash_mfma(
    const float* __restrict__ qg, const float* __restrict__ kg,
    const float* __restrict__ vg, unsigned short* __restrict__ og)
{
  const int g = blockIdx.z, hh = blockIdx.y, qt = blockIdx.x;
  const size_t base = (size_t)g * CAP_ * D_ + hh * DH_;
  const float* Q = qg + base;
  const float* Kp = kg + base;
  const float* Vp = vg + base;
  unsigned short* Ob = og + (size_t)g * CAP_ * 2 * D_ + hh * DH_;

  __shared__ __align__(16) char lds_raw[69632];
  unsigned short* Kh  = (unsigned short*)lds_raw;
  unsigned short* Kl  = Kh  + 64 * LDK;
  unsigned short* Vth = Kl  + 64 * LDK;
  unsigned short* Vtl = Vth + 64 * LDK;
  unsigned short* Ph  = Vtl + 64 * LDK;
  unsigned short* Pl  = Ph  + FBQ * LDK;
  float* Qs = (float*)lds_raw;

  const int tid = threadIdx.x;
  const int lane = tid & 63;
  const int w = tid >> 6;
  const int quad = lane >> 4;
  const int l15 = lane & 15;

  #pragma unroll
  for (int it = 0; it < 8; ++it) {
    const int row = it * 16 + (tid >> 4);
    const int c4 = (tid & 15) * 4;
    *(float4*)&Qs[row * LDQ + c4] = *(const float4*)(Q + (size_t)(qt * FBQ + row) * D_ + c4);
  }
  __syncthreads();
  FragU qf[2][2][2];
  #pragma unroll
  for (int rs = 0; rs < 2; ++rs)
    #pragma unroll
    for (int ks = 0; ks < 2; ++ks) {
      const float* p0 = &Qs[(w * 32 + rs * 16 + l15) * LDQ + ks * 32 + quad * 8];
      const float4 f0 = *(const float4*)p0;
      const float4 f1 = *(const float4*)(p0 + 4);
      split8(f0, f1, qf[rs][ks][0], qf[rs][ks][1]);
    }
  __syncthreads();

  f32x4v acc[2][4];
  float m_r[2][4], l_r[2][4];
  #pragma unroll
  for (int rs = 0; rs < 2; ++rs)
    #pragma unroll
    for (int r = 0; r < 4; ++r) { m_r[rs][r] = -1e30f; l_r[rs][r] = 0.0f; }
  #pragma unroll
  for (int rs = 0; rs < 2; ++rs)
    #pragma unroll
    for (int dt = 0; dt < 4; ++dt) { acc[rs][dt][0] = 0.f; acc[rs][dt][1] = 0.f; acc[rs][dt][2] = 0.f; acc[rs][dt][3] = 0.f; }

  for (int kt = 0; kt < 16; ++kt) {
    __syncthreads();
    #pragma unroll
    for (int it = 0; it < 4; ++it) {
      const int r = it * 16 + (tid >> 4);
      const int c4 = (tid & 15) * 4;
      const float4 kv = *(const float4*)(Kp + (size_t)(kt * 64 + r) * D_ + c4);
      {
        const unsigned u0 = __float_as_uint(kv.x), u1 = __float_as_uint(kv.y);
        const unsigned u2 = __float_as_uint(kv.z), u3 = __float_as_uint(kv.w);
        const float l0 = kv.x - __uint_as_float(u0 & 0xFFFF0000u);
        const float l1 = kv.y - __uint_as_float(u1 & 0xFFFF0000u);
        const float l2 = kv.z - __uint_as_float(u2 & 0xFFFF0000u);
        const float l3 = kv.w - __uint_as_float(u3 & 0xFFFF0000u);
        uint2 hp, lp;
        hp.x = pack_hi2(u0, u1); hp.y = pack_hi2(u2, u3);
        lp.x = pack_hi2(__float_as_uint(l0), __float_as_uint(l1));
        lp.y = pack_hi2(__float_as_uint(l2), __float_as_uint(l3));
        *(uint2*)&Kh[r * LDK + c4] = hp;
        *(uint2*)&Kl[r * LDK + c4] = lp;
      }
      const float4 vv = *(const float4*)(Vp + (size_t)(kt * 64 + r) * D_ + c4);
      const float vf[4] = {vv.x, vv.y, vv.z, vv.w};
      #pragma unroll
      for (int u = 0; u < 4; ++u) {
        const unsigned uu = __float_as_uint(vf[u]);
        const float lo = vf[u] - __uint_as_float(uu & 0xFFFF0000u);
        Vth[(c4 + u) * LDK + r] = (unsigned short)(uu >> 16);
        Vtl[(c4 + u) * LDK + r] = (unsigned short)(__float_as_uint(lo) >> 16);
      }
    }
    __syncthreads();
    f32x4v sfr[2][4];
    #pragma unroll
    for (int rs = 0; rs < 2; ++rs)
      #pragma unroll
      for (int j = 0; j < 4; ++j) {
        f32x4v s; s[0] = 0.f; s[1] = 0.f; s[2] = 0.f; s[3] = 0.f;
        #pragma unroll
        for (int ks = 0; ks < 2; ++ks) {
          FragU kh, kl;
          const unsigned short* pk = &Kh[(j * 16 + l15) * LDK + ks * 32 + quad * 8];
          const unsigned short* pl = &Kl[(j * 16 + l15) * LDK + ks * 32 + quad * 8];
          kh.u2[0] = *(const uint2*)pk; kh.u2[1] = *(const uint2*)(pk + 4);
          kl.u2[0] = *(const uint2*)pl; kl.u2[1] = *(const uint2*)(pl + 4);
          s = __builtin_amdgcn_mfma_f32_16x16x32_bf16(qf[rs][ks][0].v, kh.v, s, 0, 0, 0);
          s = __builtin_amdgcn_mfma_f32_16x16x32_bf16(qf[rs][ks][0].v, kl.v, s, 0, 0, 0);
          s = __builtin_amdgcn_mfma_f32_16x16x32_bf16(qf[rs][ks][1].v, kh.v, s, 0, 0, 0);
        }
        sfr[rs][j] = s;
      }
    #pragma unroll
    for (int rs = 0; rs < 2; ++rs) {
      #pragma unroll
      for (int r = 0; r < 4; ++r) {
        float s0 = sfr[rs][0][r] * 0.125f;
        float s1 = sfr[rs][1][r] * 0.125f;
        float s2 = sfr[rs][2][r] * 0.125f;
        float s3 = sfr[rs][3][r] * 0.125f;
        float mx = fmaxf(fmaxf(s0, s1), fmaxf(s2, s3));
        #pragma unroll
        for (int o = 1; o < 16; o <<= 1) mx = fmaxf(mx, __shfl_xor(mx, o));
        const float nm = fmaxf(m_r[rs][r], mx);
        const float al = __expf(m_r[rs][r] - nm);
        m_r[rs][r] = nm;
        const float p0 = __expf(s0 - nm);
        const float p1 = __expf(s1 - nm);
        const float p2 = __expf(s2 - nm);
        const float p3 = __expf(s3 - nm);
        float rsum = p0 + p1 + p2 + p3;
        #pragma unroll
        for (int o = 1; o < 16; o <<= 1) rsum += __shfl_xor(rsum, o);
        l_r[rs][r] = l_r[rs][r] * al + rsum;
        #pragma unroll
        for (int dt = 0; dt < 4; ++dt) acc[rs][dt][r] *= al;
        const int row = w * 32 + rs * 16 + quad * 4 + r;
        const float pv[4] = {p0, p1, p2, p3};
        #pragma unroll
        for (int j = 0; j < 4; ++j) {
          const unsigned u = __float_as_uint(pv[j]);
          const float lo = pv[j] - __uint_as_float(u & 0xFFFF0000u);
          Ph[row * LDK + j * 16 + l15] = (unsigned short)(u >> 16);
          Pl[row * LDK + j * 16 + l15] = (unsigned short)(__float_as_uint(lo) >> 16);
        }
      }
    }
    __syncthreads();
    FragU pf[2][2][2];
    #pragma unroll
    for (int rs = 0; rs < 2; ++rs)
      #pragma unroll
      for (int ks = 0; ks < 2; ++ks) {
        const unsigned short* ph = &Ph[(w * 32 + rs * 16 + l15) * LDK + ks * 32 + quad * 8];
        const unsigned short* pl = &Pl[(w * 32 + rs * 16 + l15) * LDK + ks * 32 + quad * 8];
        pf[rs][ks][0].u2[0] = *(const uint2*)ph; pf[rs][ks][0].u2[1] = *(const uint2*)(ph + 4);
        pf[rs][ks][1].u2[0] = *(const uint2*)pl; pf[rs][ks][1].u2[1] = *(const uint2*)(pl + 4);
      }
    #pragma unroll
    for (int dt = 0; dt < 4; ++dt)
      #pragma unroll
      for (int ks = 0; ks < 2; ++ks) {
        FragU vh, vl;
        const unsigned short* pv_ = &Vth[(dt * 16 + l15) * LDK + ks * 32 + quad * 8];
        const unsigned short* pl_ = &Vtl[(dt * 16 + l15) * LDK + ks * 32 + quad * 8];
        vh.u2[0] = *(const uint2*)pv_; vh.u2[1] = *(const uint2*)(pv_ + 4);
        vl.u2[0] = *(const uint2*)pl_; vl.u2[1] = *(const uint2*)(pl_ + 4);
        #pragma unroll
        for (int rs = 0; rs < 2; ++rs) {
          acc[rs][dt] = __builtin_amdgcn_mfma_f32_16x16x32_bf16(pf[rs][ks][0].v, vh.v, acc[rs][dt], 0, 0, 0);
          acc[rs][dt] = __builtin_amdgcn_mfma_f32_16x16x32_bf16(pf[rs][ks][0].v, vl.v, acc[rs][dt], 0, 0, 0);
          acc[rs][dt] = __builtin_amdgcn_mfma_f32_16x16x32_bf16(pf[rs][ks][1].v, vh.v, acc[rs][dt], 0, 0, 0);
        }
      }
  }
  // ---- epilogue: write split-bf16 ao' [CAP][2*D]
  #pragma unroll
  for (int rs = 0; rs < 2; ++rs)
    #pragma unroll
    for (int r = 0; r < 4; ++r) {
      const float inv = 1.0f / l_r[rs][r];
      const int row = qt * FBQ + w * 32 + rs * 16 + quad * 4 + r;
      #pragma unroll
      for (int dt = 0; dt < 4; ++dt) {
        const float v = acc[rs][dt][r] * inv;
        const unsigned u = __float_as_uint(v);
        const float lo = v - __uint_as_float(u & 0xFFFF0000u);
        Ob[(size_t)row * 2 * D_ + dt * 16 + l15] = (unsigned short)(u >> 16);
        Ob[(size_t)row * 2 * D_ + D_ + dt * 16 + l15] = (unsigned short)(__float_as_uint(lo) >> 16);
      }
    }
}

// ================================================================ hnew = h*(1-rho)
__global__ __launch_bounds__(256) void initnew_kernel(
    const float* __restrict__ h, const float* __restrict__ rho, float* __restrict__ hn)
{
  const int t = blockIdx.x;
  const float f = 1.0f - rho[t];
  const int c = threadIdx.x * 4;
  float4 x = *(const float4*)(h + (size_t)t * D_ + c);
  x.x *= f; x.y *= f; x.z *= f; x.w *= f;
  *(float4*)(hn + (size_t)t * D_ + c) = x;
}

// ================================================================ scatter
__global__ __launch_bounds__(256) void scatter_kernel(
    const float* __restrict__ eo, const int* __restrict__ idx, const int* __restrict__ cnt,
    const float* __restrict__ probs, float* __restrict__ hn)
{
  const int c = blockIdx.x, e = blockIdx.y;
  if (c >= cnt[e]) return;
  const int t = idx[e * CAP_ + c];
  const float w = probs[t * 8 + e];
  const float* src = eo + ((size_t)e * CAP_ + c) * D_;
  float* dst = hn + (size_t)t * D_;
  const int c4 = threadIdx.x * 4;
  #pragma unroll
  for (int j = 0; j < 4; ++j) atomicAdd(dst + c4 + j, src[c4 + j] * w);
}

// ================================================================ RMS norm
__global__ __launch_bounds__(256) void rms_kernel(
    const float* __restrict__ h, const float* __restrict__ w, float* __restrict__ out)
{
  const int t = blockIdx.x;
  const int c = threadIdx.x * 4;
  const float4 x = *(const float4*)(h + (size_t)t * D_ + c);
  float ss = x.x * x.x + x.y * x.y + x.z * x.z + x.w * x.w;
  #pragma unroll
  for (int off = 32; off > 0; off >>= 1) ss += __shfl_down(ss, off);
  __shared__ float wsum[4];
  __shared__ float sscale;
  const int lane = threadIdx.x & 63, wv = threadIdx.x >> 6;
  if (lane == 0) wsum[wv] = ss;
  __syncthreads();
  if (threadIdx.x == 0) {
    const float s = wsum[0] + wsum[1] + wsum[2] + wsum[3];
    sscale = 1.0f / sqrtf(s * (1.0f / (float)D_) + 1e-6f);
  }
  __syncthreads();
  const float sc = sscale;
  const float4 w4 = *(const float4*)(w + c);
  float4 o;
  o.x = x.x * sc * w4.x; o.y = x.y * sc * w4.y; o.z = x.z * sc * w4.z; o.w = x.w * sc * w4.w;
  *(float4*)(out + (size_t)t * D_ + c) = o;
}

// ================================================================ host
extern "C" void kernel_launch(void* const* d_in, const int* in_sizes, int n_in,
                              void* d_out, int out_size, void* d_ws, size_t ws_size,
                              hipStream_t stream)
{
  (void)in_sizes; (void)n_in; (void)out_size; (void)ws_size;
  const int* ids = (const int*)d_in[0];
  const float* embed_w = (const float*)d_in[1];
  const float* router_w = (const float*)d_in[2];
  const float* wq = (const float*)d_in[3];
  const float* wk = (const float*)d_in[4];
  const float* wv = (const float*)d_in[5];
  const float* wo = (const float*)d_in[6];
  const float* w1 = (const float*)d_in[7];
  const float* w2 = (const float*)d_in[8];
  const float* lnw = (const float*)d_in[9];
  float* out = (float*)d_out;

  float* p = (float*)d_ws;
  const size_t TD = (size_t)T_ * D_;
  float* hA = p;    p += TD;
  float* hB = p;    p += TD;
  float* probs = p; p += (size_t)T_ * E_;
  float* gmask = p; p += (size_t)E_ * T_;
  float* rho = p;   p += T_;
  int* idx = (int*)p;   p += E_ * CAP_;
  int* cnt = (int*)p;   p += 16;
  float* eo = p;   p += (size_t)E_ * CAP_ * D_;
  // qb|kb|vb|aob form a contiguous 64 MB region that mid' aliases after O-proj.
  float* qb = p;   p += (size_t)4 * CAP_ * D_;
  float* kb = p;   p += (size_t)4 * CAP_ * D_;
  float* vb = p;   p += (size_t)4 * CAP_ * D_;
  unsigned short* aob = (unsigned short*)p; p += (size_t)4 * CAP_ * D_;  // 4*CAP*2D shorts
  unsigned short* midp = (unsigned short*)qb;                            // 4*CAP*2*MLP shorts (alias)
  unsigned short* xinp = (unsigned short*)p; p += (size_t)E_ * CAP_ * D_; // E*CAP*2D shorts
  unsigned short* wqp = (unsigned short*)p; p += (size_t)4 * D_ * D_;    // [N=D][2K=2D] x4
  unsigned short* wkp = (unsigned short*)p; p += (size_t)4 * D_ * D_;
  unsigned short* wvp = (unsigned short*)p; p += (size_t)4 * D_ * D_;
  unsigned short* wop = (unsigned short*)p; p += (size_t)4 * D_ * D_;
  unsigned short* w1p = (unsigned short*)p; p += (size_t)4 * D_ * MLP_;  // [N=MLP][2K=2D] x4
  unsigned short* w2p = (unsigned short*)p; p += (size_t)4 * D_ * MLP_;  // [N=D][2K=2MLP] x4

  // one-time weight split/transpose (bf16 hi|lo, B^T layout)
  convw_kernel<<<dim3(D_ / 64, D_ / 64, 4), 256, 0, stream>>>(wq, wqp, D_, D_);
  convw_kernel<<<dim3(D_ / 64, D_ / 64, 4), 256, 0, stream>>>(wk, wkp, D_, D_);
  convw_kernel<<<dim3(D_ / 64, D_ / 64, 4), 256, 0, stream>>>(wv, wvp, D_, D_);
  convw_kernel<<<dim3(D_ / 64, D_ / 64, 4), 256, 0, stream>>>(wo, wop, D_, D_);
  convw_kernel<<<dim3(MLP_ / 64, D_ / 64, 4), 256, 0, stream>>>(w1, w1p, D_, MLP_);
  convw_kernel<<<dim3(D_ / 64, MLP_ / 64, 4), 256, 0, stream>>>(w2, w2p, MLP_, D_);

  embed_kernel<<<T_, 256, 0, stream>>>(ids, embed_w, hA);
  float* cur = hA;
  float* nxt = hB;
  for (int hop = 0; hop < HOPS_; ++hop) {
    router_kernel<<<T_, 64, 0, stream>>>(cur, router_w + (size_t)hop * 9 * D_, probs, gmask);
    zero_kernel<<<16, 256, 0, stream>>>(rho, cnt);
    select_kernel<<<dim3(16, 8), 256, 0, stream>>>(gmask, probs, idx, cnt, rho);
    gather_kernel<<<dim3(CAP_, E_), 256, 0, stream>>>(cur, idx, cnt, xinp);
    gemm_qkv_bf16<<<dim3(D_ / 128, CAP_ / 128, 12), 256, 0, stream>>>(xinp, wqp, wkp, wvp, qb, kb, vb);
    rope_kernel<<<dim3(CAP_, 4), 256, 0, stream>>>(qb, kb, idx, cnt);
    flash_mfma<<<dim3(CAP_ / FBQ, 16, 4), 256, 0, stream>>>(qb, kb, vb, aob);
    zeroeo_kernel<<<8192, 256, 0, stream>>>(eo);
    // O-proj: split-K=4, atomic accumulate into eo (attn experts)
    gemm_bf16_k<2, 4><<<dim3(D_ / 128, CAP_ / 128, 16), 256, 0, stream>>>(
        aob, wop, (void*)eo, D_, D_,
        (long)CAP_ * 2 * D_, (long)D_ * 2 * D_, (long)2 * CAP_ * D_);
    // FFN w1 (gelu epilogue -> split-bf16 mid'); mid' aliases qb..aob, so launch after O-proj.
    gemm_bf16_k<1, 1><<<dim3(MLP_ / 128, CAP_ / 128, 4), 256, 0, stream>>>(
        xinp + (size_t)CAP_ * 2 * D_, w1p, (void*)midp, MLP_, D_,
        (long)2 * CAP_ * 2 * D_, (long)MLP_ * 2 * D_, (long)CAP_ * 2 * MLP_);
    // FFN w2: split-K=4, atomic accumulate into eo (ffn experts)
    gemm_bf16_k<2, 4><<<dim3(D_ / 128, CAP_ / 128, 16), 256, 0, stream>>>(
        midp, w2p, (void*)(eo + (size_t)CAP_ * D_), D_, MLP_,
        (long)CAP_ * 2 * MLP_, (long)D_ * 2 * MLP_, (long)2 * CAP_ * D_);
    initnew_kernel<<<T_, 256, 0, stream>>>(cur, rho, nxt);
    scatter_kernel<<<dim3(CAP_, E_), 256, 0, stream>>>(eo, idx, cnt, probs, nxt);
    float* tmp = cur; cur = nxt; nxt = tmp;
  }
  rms_kernel<<<T_, 256, 0, stream>>>(cur, lnw, out);
}